// Round 4
// baseline (350.196 us; speedup 1.0000x reference)
//
#include <hip/hip_runtime.h>
#include <hip/hip_bf16.h>
#include <math.h>

#define DF 128           // feature dim (both in and out)
#define TILE_EDGES 6144  // edges per scatter tile -> 521 blocks
#define NPB 256          // nodes per bucket (bucket = col >> 8)
#define NB_MAX 512       // max buckets (supports N <= 131072)
#define KP 136           // padded K stride (bf16) for W^T LDS tile

typedef __hip_bfloat16 bf16;
typedef __hip_bfloat162 bf16x2;
typedef __attribute__((ext_vector_type(8))) short short8;
typedef __attribute__((ext_vector_type(4))) float f32x4;

__device__ inline short bf16bits(float f) {
    __hip_bfloat16 h = __float2bfloat16(f);
    return *reinterpret_cast<short*>(&h);
}

// unpack one packed bf16x2 dword (carried in a float) to 2 f32 features
__device__ inline float2 unpack2(float p) {
    unsigned u = __float_as_uint(p);
    float2 r;
    r.x = __uint_as_float(u << 16);
    r.y = __uint_as_float(u & 0xffff0000u);
    return r;
}

// ---------------- P1: bucket histogram (LDS per block, one global atomic merge) ----
__global__ __launch_bounds__(512) void k_hist(const int* __restrict__ col,
                                              int* __restrict__ bucketCnt,
                                              int E, int NB) {
    __shared__ int h[NB_MAX];
    int tid = threadIdx.x;
    for (int i = tid; i < NB; i += 512) h[i] = 0;
    __syncthreads();
    for (int e = blockIdx.x * 512 + tid; e < E; e += gridDim.x * 512)
        atomicAdd(&h[col[e] >> 8], 1);
    __syncthreads();
    for (int i = tid; i < NB; i += 512)
        if (h[i]) atomicAdd(&bucketCnt[i], h[i]);
}

// ---------------- P2: tiny scan over NB buckets (one block) ----------------
__global__ __launch_bounds__(512) void k_scanbkt(const int* __restrict__ bucketCnt,
                                                 int* __restrict__ bucketBase,
                                                 int* __restrict__ cursor,
                                                 int NB, int E) {
    __shared__ int tmp[512];
    int tid = threadIdx.x;
    int v = (tid < NB) ? bucketCnt[tid] : 0;
    tmp[tid] = v;
    __syncthreads();
    for (int off = 1; off < 512; off <<= 1) {
        int t = (tid >= off) ? tmp[tid - off] : 0;
        __syncthreads();
        tmp[tid] += t;
        __syncthreads();
    }
    if (tid < NB) {
        int excl = tmp[tid] - v;
        bucketBase[tid] = excl;
        cursor[tid] = excl;
    }
    if (tid == 0) bucketBase[NB] = E;
}

// ---------------- P3: scatter edges into buckets (atomic space reservation) -------
// binned[pos] = (localNode << 24) | row   (row < 2^24, localNode < 256)
__global__ __launch_bounds__(512) void k_binscatter(const int* __restrict__ edge,
                                                    int* __restrict__ cursor,
                                                    unsigned* __restrict__ binned,
                                                    int E, int NB) {
    __shared__ int h[NB_MAX];
    __shared__ int curl[NB_MAX];
    int tid = threadIdx.x;
    int tileBase = blockIdx.x * TILE_EDGES;
    for (int i = tid; i < NB; i += 512) h[i] = 0;
    __syncthreads();
    // pass 1: count this tile's bucket occupancy
    for (int j = 0; j < TILE_EDGES / 512; ++j) {
        int e = tileBase + j * 512 + tid;
        if (e < E) atomicAdd(&h[edge[E + e] >> 8], 1);
    }
    __syncthreads();
    // reserve contiguous space per bucket
    for (int i = tid; i < NB; i += 512)
        curl[i] = h[i] ? atomicAdd(&cursor[i], h[i]) : 0;
    __syncthreads();
    // pass 2: scatter (tile is L1/L2-hot from pass 1)
    for (int j = 0; j < TILE_EDGES / 512; ++j) {
        int e = tileBase + j * 512 + tid;
        if (e < E) {
            int r = edge[e];
            int c = edge[E + e];
            int pos = atomicAdd(&curl[c >> 8], 1);
            binned[pos] = ((unsigned)(c & (NPB - 1)) << 24) | (unsigned)r;
        }
    }
}

// ---------------- P4: per-bucket counting sort in LDS; emits CSR + deg + dinv -------
__global__ __launch_bounds__(512) void k_bucket(const unsigned* __restrict__ binned,
                                                const int* __restrict__ bucketBase,
                                                int* __restrict__ ssrc,
                                                int* __restrict__ offsets,
                                                int* __restrict__ deg,
                                                float* __restrict__ dinv, int N) {
    __shared__ int h[NPB], sc[NPB], cur[NPB];
    int tid = threadIdx.x;
    int b = blockIdx.x;
    int base = bucketBase[b];
    int cnt = bucketBase[b + 1] - base;
    if (tid < NPB) h[tid] = 0;
    __syncthreads();
    for (int i = tid; i < cnt; i += 512)
        atomicAdd(&h[binned[base + i] >> 24], 1);
    __syncthreads();
    // exclusive scan of h (256 entries)
    if (tid < NPB) sc[tid] = h[tid];
    __syncthreads();
    for (int off = 1; off < NPB; off <<= 1) {
        int tv = (tid >= off && tid < NPB) ? sc[tid - off] : 0;
        __syncthreads();
        if (tid < NPB) sc[tid] += tv;
        __syncthreads();
    }
    if (tid < NPB) {
        int excl = sc[tid] - h[tid];
        cur[tid] = base + excl;
        int node = b * NPB + tid;
        if (node < N) {
            offsets[node] = base + excl;
            deg[node] = h[tid];
            dinv[node] = rsqrtf((float)(h[tid] + 1));  // +1 self-loop
        }
    }
    __syncthreads();
    for (int i = tid; i < cnt; i += 512) {
        unsigned v = binned[base + i];
        int pos = atomicAdd(&cur[v >> 24], 1);
        ssrc[pos] = (int)(v & 0xFFFFFFu);
    }
}

// ---------------- MFMA GEMM: y = bf16((x @ W) * dinv[row]), feature-plane layout ----
// y stored as two planes y[p][node][64] (p = feature>>6), each row-slice = 128 B
// = one cache line, so the random gather in k_gather has a 12.8 MB working set
// per plane instead of 25.6 MB.
__global__ __launch_bounds__(256) void k_gemm(const float* __restrict__ x,
                                              const float* __restrict__ W,
                                              const float* __restrict__ dinv,
                                              bf16* __restrict__ y, int N) {
    __shared__ bf16 Wt[DF * KP];  // 34 KB
    int tid = threadIdx.x;
    // stage W -> Wt (transpose + f32->bf16)
    for (int i = tid; i < DF * (DF / 4); i += 256) {
        int k = i >> 5;           // 0..127
        int n4 = (i & 31) * 4;    // 0..124 step 4
        float4 w = *(const float4*)(W + k * DF + n4);
        Wt[(n4 + 0) * KP + k] = __float2bfloat16(w.x);
        Wt[(n4 + 1) * KP + k] = __float2bfloat16(w.y);
        Wt[(n4 + 2) * KP + k] = __float2bfloat16(w.z);
        Wt[(n4 + 3) * KP + k] = __float2bfloat16(w.w);
    }
    __syncthreads();

    const int wv = tid >> 6;       // wave 0..3
    const int lane = tid & 63;
    const int m16 = lane & 15;
    const int q = lane >> 4;       // quad 0..3
    const int rbase = blockIdx.x * 64 + wv * 16;
    const int arow = min(rbase + m16, N - 1);   // clamped A row for tail block

    f32x4 acc[8];
#pragma unroll
    for (int nt = 0; nt < 8; ++nt) acc[nt] = (f32x4){0.f, 0.f, 0.f, 0.f};

#pragma unroll
    for (int kc = 0; kc < 4; ++kc) {
        int k0 = kc * 32 + q * 8;
        float4 xa = *(const float4*)(x + (size_t)arow * DF + k0);
        float4 xb = *(const float4*)(x + (size_t)arow * DF + k0 + 4);
        short8 a;
        a[0] = bf16bits(xa.x); a[1] = bf16bits(xa.y);
        a[2] = bf16bits(xa.z); a[3] = bf16bits(xa.w);
        a[4] = bf16bits(xb.x); a[5] = bf16bits(xb.y);
        a[6] = bf16bits(xb.z); a[7] = bf16bits(xb.w);
#pragma unroll
        for (int nt = 0; nt < 8; ++nt) {
            short8 b = *(const short8*)(Wt + (nt * 16 + m16) * KP + k0);
            acc[nt] = __builtin_amdgcn_mfma_f32_16x16x32_bf16(a, b, acc[nt], 0, 0, 0);
        }
    }

    // epilogue: scale by dinv[row], store bf16 into feature planes
#pragma unroll
    for (int r = 0; r < 4; ++r) {
        int orow = rbase + q * 4 + r;
        if (orow < N) {
            float dv = dinv[orow];
#pragma unroll
            for (int nt = 0; nt < 8; ++nt) {
                bf16* yp = y + (size_t)(nt >> 2) * (size_t)N * 64;
                yp[(size_t)orow * 64 + (nt & 3) * 16 + m16] = __float2bfloat16(acc[nt][r] * dv);
            }
        }
    }
}

// ---------------- gather-aggregate: one wave per target node, ONE feature plane ----
// Row-slice = 32 dwords (128 B = 1 cache line). Half-wave per neighbor row:
// 32 lanes x dword; each load instruction fetches TWO rows. Per-lane-variable
// __shfl (ds_bpermute) selects the half-wave's edge directly (no cndmask).
__global__ __launch_bounds__(256) void k_gather(const float* __restrict__ yp,  // one plane, 32 dwords/row
                                                const int* __restrict__ ssrc,
                                                const int* __restrict__ offsets,
                                                const int* __restrict__ deg,
                                                const float* __restrict__ dinv,
                                                const float* __restrict__ bvec,  // plane-offset bias (64 f32)
                                                float* __restrict__ outp,        // plane-offset out (stride DF)
                                                int N) {
    int wave = (blockIdx.x * 256 + threadIdx.x) >> 6;  // 4 waves/block = 4 nodes
    int lane = threadIdx.x & 63;
    if (wave >= N) return;
    int c = wave;
    int start = offsets[c];
    int d = deg[c];
    int half = lane >> 5;   // 0/1: which edge of a pair this half-wave handles
    int l32 = lane & 31;    // covers features 2*l32, 2*l32+1 of this plane

    // self-loop term on half 0; half 1 starts at zero
    float2 acc = make_float2(0.f, 0.f);
    if (half == 0) acc = unpack2(yp[(size_t)c * 32 + l32]);

    for (int base = 0; base < d; base += 64) {
        int nb = min(64, d - base);                       // nb >= 1 here
        int idx = ssrc[start + base + min(lane, nb - 1)]; // coalesced, clamped
        int j = 0;
        for (; j + 16 <= nb; j += 16) {
            int r0 = __shfl(idx, j + 0 + half);
            int r1 = __shfl(idx, j + 2 + half);
            int r2 = __shfl(idx, j + 4 + half);
            int r3 = __shfl(idx, j + 6 + half);
            int r4 = __shfl(idx, j + 8 + half);
            int r5 = __shfl(idx, j + 10 + half);
            int r6 = __shfl(idx, j + 12 + half);
            int r7 = __shfl(idx, j + 14 + half);
            float v0 = yp[(size_t)r0 * 32 + l32];
            float v1 = yp[(size_t)r1 * 32 + l32];
            float v2 = yp[(size_t)r2 * 32 + l32];
            float v3 = yp[(size_t)r3 * 32 + l32];
            float v4 = yp[(size_t)r4 * 32 + l32];
            float v5 = yp[(size_t)r5 * 32 + l32];
            float v6 = yp[(size_t)r6 * 32 + l32];
            float v7 = yp[(size_t)r7 * 32 + l32];
            float2 u0 = unpack2(v0), u1 = unpack2(v1), u2 = unpack2(v2), u3 = unpack2(v3);
            float2 u4 = unpack2(v4), u5 = unpack2(v5), u6 = unpack2(v6), u7 = unpack2(v7);
            acc.x += ((u0.x + u1.x) + (u2.x + u3.x)) + ((u4.x + u5.x) + (u6.x + u7.x));
            acc.y += ((u0.y + u1.y) + (u2.y + u3.y)) + ((u4.y + u5.y) + (u6.y + u7.y));
        }
        for (; j + 2 <= nb; j += 2) {
            int r = __shfl(idx, j + half);
            float2 u = unpack2(yp[(size_t)r * 32 + l32]);
            acc.x += u.x;
            acc.y += u.y;
        }
        if (j < nb) {  // one leftover edge: half 0 only
            int r = __shfl(idx, j);
            if (half == 0) {
                float2 u = unpack2(yp[(size_t)r * 32 + l32]);
                acc.x += u.x;
                acc.y += u.y;
            }
        }
    }

    // combine the two half-wave partial sums
    acc.x += __shfl_xor(acc.x, 32);
    acc.y += __shfl_xor(acc.y, 32);

    if (half == 0) {
        float dv = dinv[c];
        float2 bb = *(const float2*)(bvec + l32 * 2);
        float2 o;
        o.x = fmaxf(fmaf(dv, acc.x, bb.x), 0.0f);
        o.y = fmaxf(fmaf(dv, acc.y, bb.y), 0.0f);
        *(float2*)(outp + (size_t)c * DF + l32 * 2) = o;
    }
}

extern "C" void kernel_launch(void* const* d_in, const int* in_sizes, int n_in,
                              void* d_out, int out_size, void* d_ws, size_t ws_size,
                              hipStream_t stream) {
    const float* x    = (const float*)d_in[0];
    const int*   edge = (const int*)d_in[1];   // [2, E] flat: rows then cols
    const float* W    = (const float*)d_in[2];
    const float* b    = (const float*)d_in[3];
    float*       out  = (float*)d_out;

    const int N = in_sizes[0] / DF;   // 100000
    const int E = in_sizes[1] / 2;    // 3200000

    const int T  = (E + TILE_EDGES - 1) / TILE_EDGES;   // 521 scatter tiles
    const int NB = (N + NPB - 1) / NPB;                 // 391 buckets (<= NB_MAX)

    // workspace layout (base is 16B-aligned)
    bf16*     y          = (bf16*)d_ws;              // 2 planes x N*64 bf16 (25.6 MB)
    int*      deg        = (int*)(y + (size_t)N * DF);
    float*    dinv       = (float*)(deg + N);
    int*      offsets    = (int*)(dinv + N);
    int*      bucketBase = offsets + N;              // NB+1 (pad 8)
    int*      cursor     = bucketBase + NB_MAX + 8;  // NB
    int*      bucketCnt  = cursor + NB_MAX + 8;      // NB
    unsigned* binned     = (unsigned*)(bucketCnt + NB_MAX + 8);  // E uints (12.8 MB)
    int*      ssrc       = (int*)(binned + E);       // E ints (12.8 MB)

    (void)hipMemsetAsync(bucketCnt, 0, (NB + 1) * sizeof(int), stream);
    k_hist<<<512, 512, 0, stream>>>(edge + E, bucketCnt, E, NB);
    k_scanbkt<<<1, 512, 0, stream>>>(bucketCnt, bucketBase, cursor, NB, E);
    k_binscatter<<<T, 512, 0, stream>>>(edge, cursor, binned, E, NB);
    k_bucket<<<NB, 512, 0, stream>>>(binned, bucketBase, ssrc, offsets, deg, dinv, N);
    k_gemm<<<(N + 63) / 64, 256, 0, stream>>>(x, W, dinv, y, N);
    // plane 0 then plane 1: sequential launches keep each pass's random working
    // set at 12.8 MB (one plane) for L2-hit-rate gain
    k_gather<<<(N + 3) / 4, 256, 0, stream>>>((const float*)y, ssrc, offsets, deg, dinv,
                                              b, out, N);
    k_gather<<<(N + 3) / 4, 256, 0, stream>>>((const float*)(y + (size_t)N * 64), ssrc,
                                              offsets, deg, dinv, b + 64, out + 64, N);
}